// Round 2
// baseline (425.804 us; speedup 1.0000x reference)
//
#include <hip/hip_runtime.h>

// Problem: masked mean/var normalization over time axis.
// x: (B=64, F=256, T=4000) fp32, lengths: (B,) fp32.
// For each (b,f): n = rint(lengths[b]*T); mean/var over t<n (var with n-1);
// out[b,f,t] = (x[b,f,t]-mean)/max(sqrt(var),1e-10) for ALL t.
//
// Strategy: one 256-thread block per (b,f) row. Row = 4000 floats = 1000
// float4 chunks. Each thread caches up to 4 float4 in registers (single
// global read), computes masked sum/sumsq, block-reduces (wave shfl in
// fp64 + LDS across the 4 waves), then normalizes from registers and
// writes (single global write). Memory-bound: 524 MB total traffic.

#define T_LEN   4000
#define NCHUNK  1000   // float4 chunks per row
#define EPS_STD 1e-10

__global__ __launch_bounds__(256) void mvn_kernel(
        const float* __restrict__ x,
        const float* __restrict__ lengths,
        float* __restrict__ out)
{
    const int row = blockIdx.x;            // row = b*F + f  (F=256)
    const int b   = row >> 8;
    const float* __restrict__ xr = x   + (size_t)row * T_LEN;
    float* __restrict__       orow = out + (size_t)row * T_LEN;

    const int tid = threadIdx.x;

    // n = round-half-even(lengths[b] * T), matches jnp.round
    const float nf = rintf(lengths[b] * (float)T_LEN);
    const int   n  = (int)nf;              // in [2000, 4000]

    // ---- load row into registers + masked partial sums (fp32, <=16 elems) ----
    float4 v[4];
    float s = 0.f, sq = 0.f;
    #pragma unroll
    for (int k = 0; k < 4; ++k) {
        const int c = tid + k * 256;       // chunk index
        if (c < NCHUNK) {
            v[k] = ((const float4*)xr)[c];
            const int t0 = c * 4;
            if (t0 + 3 < n) {              // fully inside mask (common case)
                s  += v[k].x + v[k].y + v[k].z + v[k].w;
                sq += v[k].x*v[k].x + v[k].y*v[k].y + v[k].z*v[k].z + v[k].w*v[k].w;
            } else if (t0 < n) {           // straddles the boundary
                if (t0 + 0 < n) { s += v[k].x; sq += v[k].x*v[k].x; }
                if (t0 + 1 < n) { s += v[k].y; sq += v[k].y*v[k].y; }
                if (t0 + 2 < n) { s += v[k].z; sq += v[k].z*v[k].z; }
                if (t0 + 3 < n) { s += v[k].w; sq += v[k].w*v[k].w; }
            }
        }
    }

    // ---- block reduction: wave64 shfl in fp64, then LDS across 4 waves ----
    double ds = (double)s, dq = (double)sq;
    #pragma unroll
    for (int off = 32; off > 0; off >>= 1) {
        ds += __shfl_down(ds, off, 64);
        dq += __shfl_down(dq, off, 64);
    }

    __shared__ double red_s[4], red_q[4];
    __shared__ float  sh_mean, sh_istd;
    const int wave = tid >> 6;
    const int lane = tid & 63;
    if (lane == 0) { red_s[wave] = ds; red_q[wave] = dq; }
    __syncthreads();

    if (tid == 0) {
        const double tot_s = red_s[0] + red_s[1] + red_s[2] + red_s[3];
        const double tot_q = red_q[0] + red_q[1] + red_q[2] + red_q[3];
        const double dn    = (double)nf;
        const double mean  = tot_s / dn;
        double var = (tot_q - dn * mean * mean) / (dn - 1.0);
        if (var < 0.0) var = 0.0;
        double std = sqrt(var);
        if (std < EPS_STD) std = EPS_STD;
        sh_mean = (float)mean;
        sh_istd = (float)(1.0 / std);
    }
    __syncthreads();

    const float mean = sh_mean;
    const float istd = sh_istd;

    // ---- normalize from registers, single write ----
    #pragma unroll
    for (int k = 0; k < 4; ++k) {
        const int c = tid + k * 256;
        if (c < NCHUNK) {
            float4 o;
            o.x = (v[k].x - mean) * istd;
            o.y = (v[k].y - mean) * istd;
            o.z = (v[k].z - mean) * istd;
            o.w = (v[k].w - mean) * istd;
            ((float4*)orow)[c] = o;
        }
    }
}

extern "C" void kernel_launch(void* const* d_in, const int* in_sizes, int n_in,
                              void* d_out, int out_size, void* d_ws, size_t ws_size,
                              hipStream_t stream) {
    const float* x       = (const float*)d_in[0];
    const float* lengths = (const float*)d_in[1];
    float* out           = (float*)d_out;

    const int B = 64, F = 256;
    const int rows = B * F;                 // 16384 blocks, 64/CU
    mvn_kernel<<<rows, 256, 0, stream>>>(x, lengths, out);
}